// Round 3
// baseline (191.569 us; speedup 1.0000x reference)
//
#include <hip/hip_runtime.h>

// PlateYoloBlock: (32,13,256,256) fp32 -> (32,65536,13) fp32
// out[b][y*256+x][c]:
//   c=0: (sigmoid(v)+x)*8   c=1: (sigmoid(v)+y)*8
//   c=2,3: exp(v)*8         c=4..11: v*8          c=12: sigmoid(v)
//
// v3b: v3 with the compile fix — __builtin_nontemporal_store requires a
// NATIVE clang vector type, not HIP's float4 class. Use ext_vector_type(4).
//  (a) NONTEMPORAL output stores: output is write-once/never-read; the nt
//      bit stops its 106MB from allocating in / evicting input from the
//      256MB Infinity Cache. Expect FETCH_SIZE 53MB -> <25MB.
//  (b) XCD-chunked bijective block swizzle (4096 % 8 == 0): resident
//      blocks on one XCD read ADJACENT tiles -> compact per-channel DRAM
//      read neighborhoods for the 13-way strided read streams.

#define NB      32
#define NC      13
#define HW      65536     // 256*256 positions per batch
#define WIDTH   256
#define TILE    512       // positions per block (divides HW; whole tile in one batch)
#define THREADS 256
#define NBLOCKS ((NB * HW) / TILE)   // 4096
#define NXCD    8
#define CHUNK   (NBLOCKS / NXCD)     // 512

typedef float v4f __attribute__((ext_vector_type(4)));

__device__ __forceinline__ float sigmoidf_(float x) {
    return 1.0f / (1.0f + __expf(-x));
}

__global__ __launch_bounds__(THREADS) void plate_yolo_kernel(
        const float* __restrict__ in, float* __restrict__ out) {
    __shared__ float lds[TILE * NC];   // 26,624 B -> 6 blocks/CU

    const int tid = threadIdx.x;

    // Bijective XCD swizzle: dispatch round-robins blockIdx%8 across XCDs;
    // remap so XCD k owns the contiguous tile range [k*512, (k+1)*512).
    const int bid = (int)blockIdx.x;
    const int swz = (bid & (NXCD - 1)) * CHUNK + (bid >> 3);

    const long long s0 = (long long)swz * TILE;          // global spatial base
    const int b = (int)(s0 >> 16);                       // 65536 positions/batch
    const int posBase = (int)(s0 & (HW - 1));
    const float* __restrict__ inB = in + (long long)b * NC * HW + posBase;

    // Stage 1: coalesced per-channel loads -> pointwise math -> LDS in output layout.
    // LDS write stride across lanes = 13 floats; gcd(13,32)=1 -> 2-way/bank (free).
    #pragma unroll
    for (int k = 0; k < TILE / THREADS; ++k) {
        const int p = tid + k * THREADS;            // local position in tile
        const int pos = posBase + p;                // position within batch
        const float fx = (float)(pos & (WIDTH - 1));
        const float fy = (float)(pos >> 8);
        #pragma unroll
        for (int c = 0; c < NC; ++c) {
            float v = inB[c * HW + p];
            float r;
            if (c == 0)                 r = (sigmoidf_(v) + fx) * 8.0f;
            else if (c == 1)            r = (sigmoidf_(v) + fy) * 8.0f;
            else if (c == 2 || c == 3)  r = __expf(v) * 8.0f;
            else if (c == 12)           r = sigmoidf_(v);
            else                        r = v * 8.0f;
            lds[p * NC + c] = r;
        }
    }
    __syncthreads();

    // Stage 2: contiguous float4 copy-out, NONTEMPORAL (no L2/L3 allocate).
    // Tile base byte offset = swz * 512*13*4 -> 16B-aligned.
    const v4f* __restrict__ src = (const v4f*)lds;
    v4f* __restrict__ dst = (v4f*)(out + s0 * NC);
    const int n4 = TILE * NC / 4;   // 1664
    #pragma unroll
    for (int j = tid; j < n4; j += THREADS) {
        __builtin_nontemporal_store(src[j], &dst[j]);
    }
}

extern "C" void kernel_launch(void* const* d_in, const int* in_sizes, int n_in,
                              void* d_out, int out_size, void* d_ws, size_t ws_size,
                              hipStream_t stream) {
    const float* in = (const float*)d_in[0];
    float* out = (float*)d_out;
    plate_yolo_kernel<<<NBLOCKS, THREADS, 0, stream>>>(in, out);
}